// Round 6
// baseline (200.600 us; speedup 1.0000x reference)
//
#include <hip/hip_runtime.h>

#define BSZ   2
#define TSEQ  2048
#define DMOD  1024
#define NHEAD 16
#define HDIM  64
#define MROW  (BSZ*TSEQ)
#define LNEPS 1e-5f
#define QSCALE 0.18033688011f   // (1/8)*log2(e): softmax in exp2 domain

typedef __bf16 bf16x8 __attribute__((ext_vector_type(8)));
typedef float  f32x4  __attribute__((ext_vector_type(4)));
typedef unsigned short us8 __attribute__((ext_vector_type(8)));
typedef unsigned short us4 __attribute__((ext_vector_type(4)));

__device__ __forceinline__ unsigned short f2bf(float f) {
    unsigned u = __float_as_uint(f);
    u += 0x7FFF + ((u >> 16) & 1);        // RNE
    return (unsigned short)(u >> 16);
}
__device__ __forceinline__ float bf2f(unsigned short u) {
    return __uint_as_float((unsigned)u << 16);
}

__device__ __forceinline__ float fexp2(float x) {
#if __has_builtin(__builtin_amdgcn_exp2f)
    return __builtin_amdgcn_exp2f(x);     // raw v_exp_f32
#else
    return __expf(x * 0.6931471805599453f);
#endif
}

__device__ __forceinline__ void gld_lds16(const void* g, void* l) {
    __builtin_amdgcn_global_load_lds(
        (const __attribute__((address_space(1))) unsigned int*)g,
        (__attribute__((address_space(3))) unsigned int*)l, 16, 0, 0);
}

// ---------------- fused prep: x->bf16 (blocks 0..2047) + 4x W^T (2048..3071)
__global__ __launch_bounds__(256) void prep_k(
    const float* __restrict__ x,
    const float* __restrict__ wq, const float* __restrict__ wk,
    const float* __restrict__ wv, const float* __restrict__ wo,
    unsigned short* __restrict__ Xb,
    unsigned short* __restrict__ WqkvT, unsigned short* __restrict__ WoT)
{
    const int tid = threadIdx.x;
    if (blockIdx.x < 2048) {
        const size_t i = ((size_t)blockIdx.x * 256 + tid) * 8;
        float4 a = *(const float4*)&x[i];
        float4 b = *(const float4*)&x[i + 4];
        union { unsigned short u[8]; uint4 v; } o;
        o.u[0]=f2bf(a.x); o.u[1]=f2bf(a.y); o.u[2]=f2bf(a.z); o.u[3]=f2bf(a.w);
        o.u[4]=f2bf(b.x); o.u[5]=f2bf(b.y); o.u[6]=f2bf(b.z); o.u[7]=f2bf(b.w);
        *(uint4*)&Xb[i] = o.v;
        return;
    }
    __shared__ float T[64][68];
    const int id = blockIdx.x - 2048;
    const int z  = id >> 8;
    const int bx = id & 15;
    const int by = (id >> 4) & 15;
    const float* W = (z == 0) ? wq : (z == 1) ? wk : (z == 2) ? wv : wo;
    unsigned short* Wt = (z < 3) ? (WqkvT + (size_t)z*1024*1024) : WoT;
    const int lr = tid >> 4, lc = (tid & 15) * 4;
    #pragma unroll
    for (int p = 0; p < 4; ++p) {
        const int kk = p*16 + lr;
        float4 v = *(const float4*)&W[(size_t)(by*64 + kk)*1024 + bx*64 + lc];
        T[lc+0][kk] = v.x; T[lc+1][kk] = v.y; T[lc+2][kk] = v.z; T[lc+3][kk] = v.w;
    }
    __syncthreads();
    #pragma unroll
    for (int p = 0; p < 2; ++p) {
        const int nl = p*32 + (tid >> 3);
        const int kb = (tid & 7) * 8;
        float4 a = *(const float4*)&T[nl][kb];
        float4 b = *(const float4*)&T[nl][kb+4];
        union { unsigned short u[8]; uint4 v; } o;
        o.u[0]=f2bf(a.x); o.u[1]=f2bf(a.y); o.u[2]=f2bf(a.z); o.u[3]=f2bf(a.w);
        o.u[4]=f2bf(b.x); o.u[5]=f2bf(b.y); o.u[6]=f2bf(b.z); o.u[7]=f2bf(b.w);
        *(uint4*)&Wt[(size_t)(bx*64 + nl)*1024 + by*64 + kb] = o.v;
    }
}

// ========== 256xN 8-phase MFMA GEMM core, templated on NB (N = NB*64) ======
#define PH_SYNC() do { __builtin_amdgcn_s_barrier(); \
    asm volatile("s_waitcnt lgkmcnt(0)" ::: "memory"); \
    __builtin_amdgcn_sched_barrier(0); } while (0)

template<int N>
__device__ __forceinline__ void vmwait() {
    if constexpr (N == 0)      asm volatile("s_waitcnt vmcnt(0)" ::: "memory");
    else if constexpr (N == 2) asm volatile("s_waitcnt vmcnt(2)" ::: "memory");
    else if constexpr (N == 3) asm volatile("s_waitcnt vmcnt(3)" ::: "memory");
    else                       asm volatile("s_waitcnt vmcnt(4)" ::: "memory");
}

template<int NB>
struct CoreT {
    const unsigned short *sA, *sB;
    unsigned short *A0w, *A1w, *B0w, *B1w;
    const unsigned short *fA0, *fA1, *fB0, *fB1;
    int swz0, swz1;
};

__device__ __forceinline__ void stageA4(const unsigned short* s, unsigned short* d) {
    #pragma unroll
    for (int u = 0; u < 4; ++u) gld_lds16(s + u*64*1024, d + u*4096);
}
template<int NB>
__device__ __forceinline__ void stageBall(const unsigned short* s, unsigned short* d) {
    #pragma unroll
    for (int u = 0; u < NB; ++u) gld_lds16(s + u*64*1024, d + u*4096);
}
__device__ __forceinline__ void stageB01(const unsigned short* s, unsigned short* d) {
    gld_lds16(s, d); gld_lds16(s + 64*1024, d + 4096);
}
template<int NB>
__device__ __forceinline__ void stageBrest(const unsigned short* s, unsigned short* d) {
    #pragma unroll
    for (int u = 2; u < NB; ++u) gld_lds16(s + u*64*1024, d + u*4096);
}

template<int NB>
__device__ __forceinline__ void core_setup(CoreT<NB>& C, unsigned short* LDS,
    const unsigned short* A, const unsigned short* Bt, int bm, int bn, int kbase)
{
    const int tid = threadIdx.x;
    const int w = tid >> 6, lane = tid & 63;
    const int quad = lane >> 4, l16 = lane & 15;
    const int wm = w >> 2, wn = w & 3;
    const int r_l = lane >> 3, c_l = lane & 7;
    C.sA = A  + (size_t)(bm + w*8 + r_l)*1024 + (c_l ^ r_l)*8 + kbase;
    C.sB = Bt + (size_t)(bn + w*8 + r_l)*1024 + (c_l ^ r_l)*8 + kbase;
    unsigned short* A0 = LDS;
    unsigned short* A1 = LDS + 16384;
    unsigned short* B0 = LDS + 32768;
    unsigned short* B1 = B0 + NB*4096;
    C.A0w = A0 + w*512; C.A1w = A1 + w*512;
    C.B0w = B0 + w*512; C.B1w = B1 + w*512;
    C.fA0 = A0 + (wm*128 + l16)*64; C.fA1 = A1 + (wm*128 + l16)*64;
    C.fB0 = B0 + (wn*NB*16 + l16)*64;  C.fB1 = B1 + (wn*NB*16 + l16)*64;
    C.swz0 = ( quad      ^ (l16 & 7)) * 8;
    C.swz1 = ((4 + quad) ^ (l16 & 7)) * 8;
}

template<int NB>
__device__ __forceinline__ void ld_b(const CoreT<NB>& C, bf16x8 (&bfr)[NB][2],
                                     const unsigned short* fB) {
    #pragma unroll
    for (int n = 0; n < NB; ++n) {
        bfr[n][0] = *(const bf16x8*)(fB + n*1024 + C.swz0);
        bfr[n][1] = *(const bf16x8*)(fB + n*1024 + C.swz1);
    }
}

template<int Q, int NB>
__device__ __forceinline__ void ld_a(const CoreT<NB>& C, bf16x8 (&af)[2][2],
                                     const unsigned short* fA) {
    #pragma unroll
    for (int dm = 0; dm < 2; ++dm) {
        af[dm][0] = *(const bf16x8*)(fA + (Q*2+dm)*1024 + C.swz0);
        af[dm][1] = *(const bf16x8*)(fA + (Q*2+dm)*1024 + C.swz1);
    }
}

template<int Q, int NB>
__device__ __forceinline__ void mma_q(f32x4 (&acc)[8][NB], bf16x8 (&af)[2][2],
                                      bf16x8 (&bfr)[NB][2]) {
    __builtin_amdgcn_s_setprio(1);
    #pragma unroll
    for (int dm = 0; dm < 2; ++dm)
        #pragma unroll
        for (int n = 0; n < NB; ++n) {
            f32x4 t = acc[Q*2+dm][n];
            t = __builtin_amdgcn_mfma_f32_16x16x32_bf16(af[dm][0], bfr[n][0], t, 0, 0, 0);
            t = __builtin_amdgcn_mfma_f32_16x16x32_bf16(af[dm][1], bfr[n][1], t, 0, 0, 0);
            acc[Q*2+dm][n] = t;
        }
    __builtin_amdgcn_s_setprio(0);
}

template<int NIT, int NB>
__device__ __forceinline__ void core_kloop(const CoreT<NB>& C, f32x4 (&acc)[8][NB])
{
    stageA4(C.sA, C.A0w);
    stageBall<NB>(C.sB,      C.B0w);
    stageBall<NB>(C.sB + 64, C.B1w);
    vmwait<NB>();
    __builtin_amdgcn_s_barrier();

    bf16x8 bfr[NB][2];
    bf16x8 af[2][2];

    #pragma unroll 1
    for (int it = 0; it < NIT - 1; ++it) {
        const int kk = it * 128;
        ld_b<NB>(C, bfr, C.fB0);
        ld_a<0,NB>(C, af, C.fA0);
        stageA4(C.sA + kk + 64, C.A1w);
        PH_SYNC();  mma_q<0,NB>(acc, af, bfr);
        __builtin_amdgcn_s_barrier();
        ld_a<1,NB>(C, af, C.fA0);
        stageB01(C.sB + kk + 128, C.B0w);
        PH_SYNC();  mma_q<1,NB>(acc, af, bfr);
        __builtin_amdgcn_s_barrier();
        ld_a<2,NB>(C, af, C.fA0);
        stageBrest<NB>(C.sB + kk + 128, C.B0w);
        PH_SYNC();  mma_q<2,NB>(acc, af, bfr);
        __builtin_amdgcn_s_barrier();
        ld_a<3,NB>(C, af, C.fA0);
        PH_SYNC();  mma_q<3,NB>(acc, af, bfr);
        vmwait<NB>();
        __builtin_amdgcn_s_barrier();
        ld_b<NB>(C, bfr, C.fB1);
        ld_a<0,NB>(C, af, C.fA1);
        stageA4(C.sA + kk + 128, C.A0w);
        PH_SYNC();  mma_q<0,NB>(acc, af, bfr);
        __builtin_amdgcn_s_barrier();
        ld_a<1,NB>(C, af, C.fA1);
        stageB01(C.sB + kk + 192, C.B1w);
        PH_SYNC();  mma_q<1,NB>(acc, af, bfr);
        __builtin_amdgcn_s_barrier();
        ld_a<2,NB>(C, af, C.fA1);
        stageBrest<NB>(C.sB + kk + 192, C.B1w);
        PH_SYNC();  mma_q<2,NB>(acc, af, bfr);
        __builtin_amdgcn_s_barrier();
        ld_a<3,NB>(C, af, C.fA1);
        PH_SYNC();  mma_q<3,NB>(acc, af, bfr);
        vmwait<NB>();
        __builtin_amdgcn_s_barrier();
    }
    {
        const int kk = (NIT - 1) * 128;
        ld_b<NB>(C, bfr, C.fB0);
        ld_a<0,NB>(C, af, C.fA0);
        stageA4(C.sA + kk + 64, C.A1w);
        PH_SYNC();  mma_q<0,NB>(acc, af, bfr);
        __builtin_amdgcn_s_barrier();
        ld_a<1,NB>(C, af, C.fA0); PH_SYNC(); mma_q<1,NB>(acc, af, bfr); __builtin_amdgcn_s_barrier();
        ld_a<2,NB>(C, af, C.fA0); PH_SYNC(); mma_q<2,NB>(acc, af, bfr); __builtin_amdgcn_s_barrier();
        ld_a<3,NB>(C, af, C.fA0); PH_SYNC(); mma_q<3,NB>(acc, af, bfr);
        vmwait<0>();
        __builtin_amdgcn_s_barrier();
        ld_b<NB>(C, bfr, C.fB1);
        ld_a<0,NB>(C, af, C.fA1); PH_SYNC(); mma_q<0,NB>(acc, af, bfr); __builtin_amdgcn_s_barrier();
        ld_a<1,NB>(C, af, C.fA1); PH_SYNC(); mma_q<1,NB>(acc, af, bfr); __builtin_amdgcn_s_barrier();
        ld_a<2,NB>(C, af, C.fA1); PH_SYNC(); mma_q<2,NB>(acc, af, bfr); __builtin_amdgcn_s_barrier();
        ld_a<3,NB>(C, af, C.fA1); PH_SYNC(); mma_q<3,NB>(acc, af, bfr);
    }
}

// ------ QKV GEMM: M=4096 N=3072 K=1024, 256x192 tiles -> 256 blocks --------
__global__ __launch_bounds__(512, 1) void gemm_qkv_k(
    const unsigned short* __restrict__ A, const unsigned short* __restrict__ Bt,
    const float* __restrict__ b0, const float* __restrict__ b1,
    const float* __restrict__ b2,
    unsigned short* __restrict__ oQ, unsigned short* __restrict__ oK,
    unsigned short* __restrict__ oV)
{
    extern __shared__ unsigned short LDS[];
    const int ob = blockIdx.x;
    const int wg = (ob & 7) * 32 + (ob >> 3);
    const int by = wg >> 4, bx = wg & 15;
    const int bm = by * 256, bn = bx * 192;

    CoreT<3> C;
    core_setup<3>(C, LDS, A, Bt, bm, bn, 0);

    f32x4 acc[8][3];
    #pragma unroll
    for (int i = 0; i < 8; ++i)
        #pragma unroll
        for (int j = 0; j < 3; ++j) acc[i][j] = (f32x4){0.f,0.f,0.f,0.f};

    core_kloop<8,3>(C, acc);

    const int tid = threadIdx.x;
    const int w = tid >> 6, lane = tid & 63;
    const int quad = lane >> 4, l16 = lane & 15;
    const int wm = w >> 2, wn = w & 3;
    #pragma unroll
    for (int n = 0; n < 3; ++n) {
        const int c0  = bn + wn*48 + n*16;
        const int seg = c0 >> 10;
        const int cl0 = c0 & 1023;
        if (seg < 2) {
            unsigned short* O = (seg == 0) ? oQ : oK;
            const float sc = (seg == 0) ? QSCALE : 1.0f;
            const float* bias = (seg == 0) ? b0 : b1;
            const int col = cl0 + l16;
            const float bs = bias[col];
            #pragma unroll
            for (int m = 0; m < 8; ++m)
                #pragma unroll
                for (int r = 0; r < 4; ++r) {
                    const int grow = bm + wm*128 + m*16 + quad*4 + r;
                    O[(size_t)grow*1024 + col] = f2bf((acc[m][n][r] + bs) * sc);
                }
        } else {
            const int ch = cl0 + l16;
            const float bs = b2[ch];
            #pragma unroll
            for (int m = 0; m < 8; ++m) {
                const int grow0 = bm + wm*128 + m*16 + quad*4;
                us4 o;
                #pragma unroll
                for (int r = 0; r < 4; ++r) o[r] = f2bf(acc[m][n][r] + bs);
                *(us4*)&oV[(size_t)ch*MROW + grow0] = o;
            }
        }
    }
}

// ------ proj GEMM: 256x128 tiles, split-K=2 -> 256 blocks (round-4 best) ---
__global__ __launch_bounds__(512, 2) void gemm_proj_k(
    const unsigned short* __restrict__ A, const unsigned short* __restrict__ Bt,
    unsigned short* __restrict__ P)   // [2][MROW][1024]
{
    extern __shared__ unsigned short LDS[];
    const int ob = blockIdx.x;
    const int wg = (ob & 7) * 16 + (ob >> 3);
    const int by = wg >> 3, bx = wg & 7;
    const int kz = blockIdx.y;
    const int bm = by * 256, bn = bx * 128;

    CoreT<2> C;
    core_setup<2>(C, LDS, A, Bt, bm, bn, kz * 512);

    f32x4 acc[8][2];
    #pragma unroll
    for (int i = 0; i < 8; ++i)
        #pragma unroll
        for (int j = 0; j < 2; ++j) acc[i][j] = (f32x4){0.f,0.f,0.f,0.f};

    core_kloop<4,2>(C, acc);

    const int tid = threadIdx.x;
    const int w = tid >> 6, lane = tid & 63;
    const int quad = lane >> 4, l16 = lane & 15;
    const int wm = w >> 2, wn = w & 3;
    unsigned short* O = P + (size_t)kz*MROW*1024;
    #pragma unroll
    for (int n = 0; n < 2; ++n) {
        const int col = bn + wn*32 + n*16 + l16;
        #pragma unroll
        for (int m = 0; m < 8; ++m)
            #pragma unroll
            for (int r = 0; r < 4; ++r) {
                const int grow = bm + wm*128 + m*16 + quad*4 + r;
                O[(size_t)grow*1024 + col] = f2bf(acc[m][n][r]);
            }
    }
}

// ---------------- flash attention v7: KVBLK=128, half the sync events ------
// Block = 64 q x 4 waves; single-buffered K[128][64] + V^T[64][128] = 32 KB
// -> still 4 blocks/CU, but 16 iterations (sync/drain events halved at
// constant MFMA work: 36 MFMA/iter/wave). wq = q-half, wk = 64-kv half;
// per wk-half: 2 kv-groups of 32 (g=0,1), each the proven v6 inner body.
__global__ __launch_bounds__(256, 4) void attn_k(
    const unsigned short* __restrict__ Qg,
    const unsigned short* __restrict__ Kg,
    const unsigned short* __restrict__ Vtg,
    unsigned short* __restrict__ CTX)
{
    extern __shared__ __align__(16) char lds_raw[];
    unsigned short* Ks = (unsigned short*)lds_raw;            // [128][64] swz
    unsigned short* Vs = (unsigned short*)(lds_raw + 16384);  // [64 d][128 kv] swz
    unsigned short* Qs = (unsigned short*)lds_raw;            // [64][72] transient
    float* Od = (float*)lds_raw;                              // [2][32][68] transient
    float* Ld = (float*)(lds_raw + 32768);                    // [64]

    const int tid  = threadIdx.x;
    const int wv   = tid >> 6;
    const int lane = tid & 63;
    const int quad = lane >> 4;
    const int l16  = lane & 15;
    const int wq   = wv & 1;
    const int wk   = wv >> 1;

    const int n    = blockIdx.x;
    const int slot = n >> 3;
    const int grp  = (n & 7) + 8 * (slot >> 5);
    const int qx   = slot & 31;
    const int h    = grp >> 1;
    const int b    = grp & 1;
    const int qb   = qx * 64;

    {   // Q: 64 rows x 64 cols -> Qs[64][72]
        const int r  = tid >> 2;
        const int cb = (tid & 3) * 16;
        const unsigned short* Qrow = Qg + ((size_t)(b*TSEQ + qb + r))*DMOD + h*HDIM + cb;
        *(us8*)&Qs[r*72 + cb]     = *(const us8*)&Qrow[0];
        *(us8*)&Qs[r*72 + cb + 8] = *(const us8*)&Qrow[8];
    }
    __syncthreads();
    bf16x8 qf[2][2];
    #pragma unroll
    for (int nt = 0; nt < 2; ++nt)
        #pragma unroll
        for (int kh = 0; kh < 2; ++kh)
            qf[nt][kh] = *(const bf16x8*)&Qs[(wq*32 + nt*16 + l16)*72 + kh*32 + quad*8];
    __syncthreads();   // Qs region free for K/V staging

    // staging: waves 0,1 -> K rows [part*64, part*64+64); waves 2,3 -> V d-rows
    const bool isK = (wv < 2);
    const int part = wv & 1;
    const unsigned short* gbase;
    unsigned int goff[8];
    unsigned short* ldst;
    if (isK) {
        const int sr = lane >> 3, sc = lane & 7;
        gbase = Kg + ((size_t)(b*TSEQ))*DMOD + h*HDIM;
        #pragma unroll
        for (int s = 0; s < 8; ++s) {
            const int R = part*64 + s*8 + sr;
            const int gc = sc ^ ((R ^ (R >> 2)) & 7);
            goff[s] = (unsigned)(R*DMOD + gc*8);
        }
        ldst = Ks + part*4096;
    } else {
        const int vr = lane >> 4;      // row within 4-row unit
        const int cl = lane & 15;      // 16 chunks per 128-short row
        gbase = Vtg + ((size_t)(h*HDIM))*MROW + b*TSEQ;
        #pragma unroll
        for (int s = 0; s < 8; ++s) {
            const int d = part*32 + s*4 + vr;
            const int gc = cl ^ (d & 15);
            goff[s] = (unsigned)(d*MROW + gc*8);
        }
        ldst = Vs + part*4096;
    }
    const size_t gstep = isK ? (size_t)128*DMOD : (size_t)128;

    // loop-invariant LDS read offsets
    const int rowA_l = (l16 >> 2)*8 + (l16 & 3);
    const unsigned short* kp[2][4];
    const unsigned short* vp[2][4];
    #pragma unroll
    for (int g = 0; g < 2; ++g) {
        const int rA = wk*64 + g*32 + rowA_l;
        const int rB = rA + 4;
        const int swA = (rA ^ (rA >> 2)) & 7;
        const int swB = (rB ^ (rB >> 2)) & 7;
        kp[g][0] = &Ks[rA*64 + (( quad      ^ swA))*8];
        kp[g][1] = &Ks[rA*64 + (((4 + quad) ^ swA))*8];
        kp[g][2] = &Ks[rB*64 + (( quad      ^ swB))*8];
        kp[g][3] = &Ks[rB*64 + (((4 + quad) ^ swB))*8];
        #pragma unroll
        for (int dt = 0; dt < 4; ++dt)
            vp[g][dt] = &Vs[(dt*16 + l16)*128 + (((wk*8 + g*4 + quad) ^ l16))*8];
    }

    bf16x8 onef;
    { union { unsigned short u[8]; bf16x8 v; } o1;
      #pragma unroll
      for (int i = 0; i < 8; ++i) o1.u[i] = 0x3F80;
      onef = o1.v; }

    f32x4 oacc[4][2];
    f32x4 lacc[2];
    #pragma unroll
    for (int dt = 0; dt < 4; ++dt)
        #pragma unroll
        for (int nt = 0; nt < 2; ++nt) oacc[dt][nt] = (f32x4){0.f,0.f,0.f,0.f};
    lacc[0] = (f32x4){0.f,0.f,0.f,0.f};
    lacc[1] = (f32x4){0.f,0.f,0.f,0.f};

    #pragma unroll 1
    for (int it = 0; it < 16; ++it) {
        __syncthreads();
        #pragma unroll
        for (int s = 0; s < 8; ++s)
            gld_lds16(gbase + (size_t)it*gstep + goff[s], ldst + s*512);
        __syncthreads();

        #pragma unroll
        for (int g = 0; g < 2; ++g) {
            bf16x8 ka0 = *(const bf16x8*)kp[g][0];
            bf16x8 ka1 = *(const bf16x8*)kp[g][1];
            bf16x8 kb0 = *(const bf16x8*)kp[g][2];
            bf16x8 kb1 = *(const bf16x8*)kp[g][3];
            bf16x8 vf[4];
            #pragma unroll
            for (int dt = 0; dt < 4; ++dt) vf[dt] = *(const bf16x8*)vp[g][dt];

            bf16x8 pf[2];
            #pragma unroll
            for (int nt = 0; nt < 2; ++nt) {
                f32x4 z = (f32x4){0.f,0.f,0.f,0.f};
                z = __builtin_amdgcn_mfma_f32_16x16x32_bf16(ka0, qf[nt][0], z, 0, 0, 0);
                f32x4 sA = __builtin_amdgcn_mfma_f32_16x16x32_bf16(ka1, qf[nt][1], z, 0, 0, 0);
                f32x4 z2 = (f32x4){0.f,0.f,0.f,0.f};
                z2 = __builtin_amdgcn_mfma_f32_16x16x32_bf16(kb0, qf[nt][0], z2, 0, 0, 0);
                f32x4 sB = __builtin_amdgcn_mfma_f32_16x16x32_bf16(kb1, qf[nt][1], z2, 0, 0, 0);
                float eA[4], eB[4];
                #pragma unroll
                for (int r = 0; r < 4; ++r) { eA[r] = fexp2(sA[r]); eB[r] = fexp2(sB[r]); }
                union { unsigned d[4]; bf16x8 v; } up;
                up.d[0] = __builtin_amdgcn_perm(__float_as_uint(eA[1]), __float_as_uint(eA[0]), 0x07060302);
                up.d[1] = __builtin_amdgcn_perm(__float_as_uint(eA[3]), __float_as_uint(eA[2]), 0x07060302);
                up.d[2] = __builtin_amdgcn_perm(__float_as_uint(eB[1]), __float_as_uint(eB[0]), 0x07060302);
                up.d[3] = __builtin_amdgcn_perm(__float_as_uint(eB[3]), __float_as_uint(eB[2]), 0x07060302);
                pf[nt] = up.v;
            }
            __builtin_amdgcn_s_setprio(1);
            #pragma unroll
            for (int nt = 0; nt < 2; ++nt) {
                lacc[nt] = __builtin_amdgcn_mfma_f32_16x16x32_bf16(onef, pf[nt], lacc[nt], 0, 0, 0);
                #pragma unroll
                for (int dt = 0; dt < 4; ++dt)
                    oacc[dt][nt] = __builtin_amdgcn_mfma_f32_16x16x32_bf16(vf[dt], pf[nt], oacc[dt][nt], 0, 0, 0);
            }
            __builtin_amdgcn_s_setprio(0);
        }
    }

    __syncthreads();   // all K/V reads done; Od/Ld overlay now safe
    if (wk == 0) {
        float* od = Od + wq*32*68;
        #pragma unroll
        for (int nt = 0; nt < 2; ++nt) {
            #pragma unroll
            for (int dt = 0; dt < 4; ++dt)
                *(f32x4*)&od[(nt*16 + l16)*68 + dt*16 + quad*4] = oacc[dt][nt];
            if (quad == 0) Ld[wq*32 + nt*16 + l16] = lacc[nt][0];
        }
    }
    __syncthreads();
    if (wk == 1) {
        const float* od = Od + wq*32*68;
        #pragma unroll
        for (int nt = 0; nt < 2; ++nt) {
            const float l = Ld[wq*32 + nt*16 + l16] + lacc[nt][0];
            const float inv = 1.f / l;
            const int q = qb + wq*32 + nt*16 + l16;
            unsigned short* crow = CTX + ((size_t)(b*TSEQ + q))*DMOD + h*HDIM;
            #pragma unroll
            for (int dt = 0; dt < 4; ++dt) {
                f32x4 p = *(const f32x4*)&od[(nt*16 + l16)*68 + dt*16 + quad*4];
                us4 o;
                #pragma unroll
                for (int r = 0; r < 4; ++r) o[r] = f2bf((p[r] + oacc[dt][nt][r]) * inv);
                *(us4*)&crow[dt*16 + quad*4] = o;
            }
        }
    }
}

// ---------- split-K reduce + bias + residual + LayerNorm -------------------
__global__ __launch_bounds__(256) void red_ln_k(
    const float* __restrict__ x, const unsigned short* __restrict__ P,
    const float* __restrict__ bo,
    const float* __restrict__ gamma, const float* __restrict__ beta,
    float* __restrict__ out)
{
    __shared__ float rs[4], rss[4];
    const int row = blockIdx.x;
    const int tid = threadIdx.x;
    const int c = tid * 4;
    const float4 xv = *(const float4*)&x[(size_t)row*DMOD + c];
    const us4 p0 = *(const us4*)&P[(size_t)row*DMOD + c];
    const us4 p1 = *(const us4*)&P[(size_t)(MROW + row)*DMOD + c];
    const float4 bv4 = *(const float4*)&bo[c];
    const float v0 = xv.x + bf2f(p0[0]) + bf2f(p1[0]) + bv4.x;
    const float v1 = xv.y + bf2f(p0[1]) + bf2f(p1[1]) + bv4.y;
    const float v2 = xv.z + bf2f(p0[2]) + bf2f(p1[2]) + bv4.z;
    const float v3 = xv.w + bf2f(p0[3]) + bf2f(p1[3]) + bv4.w;
    float s  = v0 + v1 + v2 + v3;
    float ss = v0*v0 + v1*v1 + v2*v2 + v3*v3;
    #pragma unroll
    for (int o = 32; o > 0; o >>= 1) {
        s  += __shfl_down(s,  o, 64);
        ss += __shfl_down(ss, o, 64);
    }
    if ((tid & 63) == 0) { rs[tid >> 6] = s; rss[tid >> 6] = ss; }
    __syncthreads();
    s  = rs[0] + rs[1] + rs[2] + rs[3];
    ss = rss[0] + rss[1] + rss[2] + rss[3];
    const float mean = s * (1.f/DMOD);
    const float var  = ss * (1.f/DMOD) - mean*mean;
    const float rstd = rsqrtf(var + LNEPS);
    const float4 gv = *(const float4*)&gamma[c];
    const float4 bv = *(const float4*)&beta[c];
    float4 o;
    o.x = (v0 - mean)*rstd*gv.x + bv.x;
    o.y = (v1 - mean)*rstd*gv.y + bv.y;
    o.z = (v2 - mean)*rstd*gv.z + bv.z;
    o.w = (v3 - mean)*rstd*gv.w + bv.w;
    *(float4*)&out[(size_t)row*DMOD + c] = o;
}

extern "C" void kernel_launch(void* const* d_in, const int* in_sizes, int n_in,
                              void* d_out, int out_size, void* d_ws, size_t ws_size,
                              hipStream_t stream) {
    const float* x     = (const float*)d_in[0];
    const float* wq    = (const float*)d_in[1];
    const float* bq    = (const float*)d_in[2];
    const float* wk    = (const float*)d_in[3];
    const float* bk    = (const float*)d_in[4];
    const float* wvp   = (const float*)d_in[5];
    const float* bvp   = (const float*)d_in[6];
    const float* wo    = (const float*)d_in[7];
    const float* bo    = (const float*)d_in[8];
    const float* gamma = (const float*)d_in[9];
    const float* beta  = (const float*)d_in[10];
    float* out = (float*)d_out;

    // ws layout (bf16 elems)
    unsigned short* Xb    = (unsigned short*)d_ws;          // [4096][1024]
    unsigned short* WqkvT = Xb    + (size_t)MROW*DMOD;      // [3072][1024]
    unsigned short* WoT   = WqkvT + (size_t)3072*1024;      // [1024][1024]
    unsigned short* Qb    = WoT   + (size_t)1024*1024;      // [4096][1024]
    unsigned short* Kb    = Qb    + (size_t)MROW*DMOD;      // [4096][1024]
    unsigned short* VtG   = Kb    + (size_t)MROW*DMOD;      // [1024][4096]
    unsigned short* CTXb  = VtG   + (size_t)DMOD*MROW;      // [4096][1024]
    unsigned short* Pp    = CTXb  + (size_t)MROW*DMOD;      // [2][4096][1024]

    prep_k<<<3072, 256, 0, stream>>>(x, wq, wk, wvp, wo, Xb, WqkvT, WoT);

    gemm_qkv_k<<<dim3(256), 512, 114688, stream>>>(
        Xb, WqkvT, bq, bk, bvp, Qb, Kb, VtG);

    attn_k<<<dim3(1024), 256, 33024, stream>>>(Qb, Kb, VtG, CTXb);

    gemm_proj_k<<<dim3(128, 2), 512, 98304, stream>>>(CTXb, WoT, Pp);

    red_ln_k<<<MROW, 256, 0, stream>>>(x, Pp, bo, gamma, beta, out);
}

// Round 7
// 187.142 us; speedup vs baseline: 1.0719x; 1.0719x over previous
//
#include <hip/hip_runtime.h>

#define BSZ   2
#define TSEQ  2048
#define DMOD  1024
#define NHEAD 16
#define HDIM  64
#define MROW  (BSZ*TSEQ)
#define LNEPS 1e-5f
#define QSCALE 0.18033688011f   // (1/8)*log2(e): softmax in exp2 domain

typedef __bf16 bf16x8 __attribute__((ext_vector_type(8)));
typedef float  f32x4  __attribute__((ext_vector_type(4)));
typedef unsigned short us8 __attribute__((ext_vector_type(8)));
typedef unsigned short us4 __attribute__((ext_vector_type(4)));

__device__ __forceinline__ unsigned short f2bf(float f) {
    unsigned u = __float_as_uint(f);
    u += 0x7FFF + ((u >> 16) & 1);        // RNE
    return (unsigned short)(u >> 16);
}
__device__ __forceinline__ float bf2f(unsigned short u) {
    return __uint_as_float((unsigned)u << 16);
}

__device__ __forceinline__ float fexp2(float x) {
#if __has_builtin(__builtin_amdgcn_exp2f)
    return __builtin_amdgcn_exp2f(x);     // raw v_exp_f32
#else
    return __expf(x * 0.6931471805599453f);
#endif
}

__device__ __forceinline__ void gld_lds16(const void* g, void* l) {
    __builtin_amdgcn_global_load_lds(
        (const __attribute__((address_space(1))) unsigned int*)g,
        (__attribute__((address_space(3))) unsigned int*)l, 16, 0, 0);
}

// ---------------- fused prep: x->bf16 (blocks 0..2047) + 4x W^T (2048..3071)
__global__ __launch_bounds__(256) void prep_k(
    const float* __restrict__ x,
    const float* __restrict__ wq, const float* __restrict__ wk,
    const float* __restrict__ wv, const float* __restrict__ wo,
    unsigned short* __restrict__ Xb,
    unsigned short* __restrict__ WqkvT, unsigned short* __restrict__ WoT)
{
    const int tid = threadIdx.x;
    if (blockIdx.x < 2048) {
        const size_t i = ((size_t)blockIdx.x * 256 + tid) * 8;
        float4 a = *(const float4*)&x[i];
        float4 b = *(const float4*)&x[i + 4];
        union { unsigned short u[8]; uint4 v; } o;
        o.u[0]=f2bf(a.x); o.u[1]=f2bf(a.y); o.u[2]=f2bf(a.z); o.u[3]=f2bf(a.w);
        o.u[4]=f2bf(b.x); o.u[5]=f2bf(b.y); o.u[6]=f2bf(b.z); o.u[7]=f2bf(b.w);
        *(uint4*)&Xb[i] = o.v;
        return;
    }
    __shared__ float T[64][68];
    const int id = blockIdx.x - 2048;
    const int z  = id >> 8;
    const int bx = id & 15;
    const int by = (id >> 4) & 15;
    const float* W = (z == 0) ? wq : (z == 1) ? wk : (z == 2) ? wv : wo;
    unsigned short* Wt = (z < 3) ? (WqkvT + (size_t)z*1024*1024) : WoT;
    const int lr = tid >> 4, lc = (tid & 15) * 4;
    #pragma unroll
    for (int p = 0; p < 4; ++p) {
        const int kk = p*16 + lr;
        float4 v = *(const float4*)&W[(size_t)(by*64 + kk)*1024 + bx*64 + lc];
        T[lc+0][kk] = v.x; T[lc+1][kk] = v.y; T[lc+2][kk] = v.z; T[lc+3][kk] = v.w;
    }
    __syncthreads();
    #pragma unroll
    for (int p = 0; p < 2; ++p) {
        const int nl = p*32 + (tid >> 3);
        const int kb = (tid & 7) * 8;
        float4 a = *(const float4*)&T[nl][kb];
        float4 b = *(const float4*)&T[nl][kb+4];
        union { unsigned short u[8]; uint4 v; } o;
        o.u[0]=f2bf(a.x); o.u[1]=f2bf(a.y); o.u[2]=f2bf(a.z); o.u[3]=f2bf(a.w);
        o.u[4]=f2bf(b.x); o.u[5]=f2bf(b.y); o.u[6]=f2bf(b.z); o.u[7]=f2bf(b.w);
        *(uint4*)&Wt[(size_t)(bx*64 + nl)*1024 + by*64 + kb] = o.v;
    }
}

// ======== CoreP: 128x128-tile 8-phase core, 256 threads, 2 blocks/CU =======
// 4 waves (2M x 2N), per-wave 64x64 output, BK=64. Stage unit = 32 rows
// (256 thr x 16B). A tile = 4 units, B tile = 4 units. LDS 64 KB ->
// 2 INDEPENDENT blocks per CU: cross-block antiphase fills MFMA/LDS bubbles.
// chunk-XOR swizzle + counted vmcnt(4) at P4/P8 only.

#define PH_SYNC() do { __builtin_amdgcn_s_barrier(); \
    asm volatile("s_waitcnt lgkmcnt(0)" ::: "memory"); \
    __builtin_amdgcn_sched_barrier(0); } while (0)

template<int N>
__device__ __forceinline__ void vmwait() {
    if constexpr (N == 0)      asm volatile("s_waitcnt vmcnt(0)" ::: "memory");
    else                       asm volatile("s_waitcnt vmcnt(4)" ::: "memory");
}

struct CoreP {
    const unsigned short *sA, *sB;
    unsigned short *A0w, *A1w, *B0w, *B1w;
    const unsigned short *fA0, *fA1, *fB0, *fB1;
    int swz0, swz1;
};

__device__ __forceinline__ void stage4p(const unsigned short* s, unsigned short* d) {
    #pragma unroll
    for (int u = 0; u < 4; ++u) gld_lds16(s + u*32*1024, d + u*2048);
}
__device__ __forceinline__ void stage01p(const unsigned short* s, unsigned short* d) {
    gld_lds16(s, d); gld_lds16(s + 32*1024, d + 2048);
}
__device__ __forceinline__ void stage23p(const unsigned short* s, unsigned short* d) {
    gld_lds16(s + 2*32*1024, d + 2*2048); gld_lds16(s + 3*32*1024, d + 3*2048);
}

__device__ __forceinline__ void corep_setup(CoreP& C, unsigned short* LDS,
    const unsigned short* A, const unsigned short* Bt, int bm, int bn, int kbase)
{
    const int tid = threadIdx.x;
    const int w = tid >> 6, lane = tid & 63;
    const int quad = lane >> 4, l16 = lane & 15;
    const int wm = w >> 1, wn = w & 1;
    const int r_l = lane >> 3, c_l = lane & 7;
    C.sA = A  + (size_t)(bm + w*8 + r_l)*1024 + (c_l ^ r_l)*8 + kbase;
    C.sB = Bt + (size_t)(bn + w*8 + r_l)*1024 + (c_l ^ r_l)*8 + kbase;
    unsigned short* A0 = LDS;            // 128x64 = 8192 shorts
    unsigned short* A1 = LDS + 8192;
    unsigned short* B0 = LDS + 16384;
    unsigned short* B1 = LDS + 24576;
    C.A0w = A0 + w*512; C.A1w = A1 + w*512;
    C.B0w = B0 + w*512; C.B1w = B1 + w*512;
    C.fA0 = A0 + (wm*64 + l16)*64; C.fA1 = A1 + (wm*64 + l16)*64;
    C.fB0 = B0 + (wn*64 + l16)*64; C.fB1 = B1 + (wn*64 + l16)*64;
    C.swz0 = ( quad      ^ (l16 & 7)) * 8;
    C.swz1 = ((4 + quad) ^ (l16 & 7)) * 8;
}

__device__ __forceinline__ void ld_bp(const CoreP& C, bf16x8 (&bfr)[4][2],
                                      const unsigned short* fB) {
    #pragma unroll
    for (int n = 0; n < 4; ++n) {
        bfr[n][0] = *(const bf16x8*)(fB + n*1024 + C.swz0);
        bfr[n][1] = *(const bf16x8*)(fB + n*1024 + C.swz1);
    }
}
template<int Q>
__device__ __forceinline__ void ld_ap(const CoreP& C, bf16x8 (&af)[2],
                                      const unsigned short* fA) {
    af[0] = *(const bf16x8*)(fA + Q*1024 + C.swz0);
    af[1] = *(const bf16x8*)(fA + Q*1024 + C.swz1);
}
template<int Q>
__device__ __forceinline__ void mma_p(f32x4 (&acc)[4][4], bf16x8 (&af)[2],
                                      bf16x8 (&bfr)[4][2]) {
    __builtin_amdgcn_s_setprio(1);
    #pragma unroll
    for (int n = 0; n < 4; ++n) {
        f32x4 t = acc[Q][n];
        t = __builtin_amdgcn_mfma_f32_16x16x32_bf16(af[0], bfr[n][0], t, 0, 0, 0);
        t = __builtin_amdgcn_mfma_f32_16x16x32_bf16(af[1], bfr[n][1], t, 0, 0, 0);
        acc[Q][n] = t;
    }
    __builtin_amdgcn_s_setprio(0);
}

template<int NIT>
__device__ __forceinline__ void corep_kloop(const CoreP& C, f32x4 (&acc)[4][4])
{
    stage4p(C.sA, C.A0w);
    stage4p(C.sB, C.B0w);
    stage4p(C.sB + 64, C.B1w);
    vmwait<4>();
    __builtin_amdgcn_s_barrier();

    bf16x8 bfr[4][2];
    bf16x8 af[2];

    #pragma unroll 1
    for (int it = 0; it < NIT - 1; ++it) {
        const int kk = it * 128;
        ld_bp(C, bfr, C.fB0);
        ld_ap<0>(C, af, C.fA0);
        stage4p(C.sA + kk + 64, C.A1w);
        PH_SYNC();  mma_p<0>(acc, af, bfr);
        __builtin_amdgcn_s_barrier();
        ld_ap<1>(C, af, C.fA0);
        stage01p(C.sB + kk + 128, C.B0w);
        PH_SYNC();  mma_p<1>(acc, af, bfr);
        __builtin_amdgcn_s_barrier();
        ld_ap<2>(C, af, C.fA0);
        stage23p(C.sB + kk + 128, C.B0w);
        PH_SYNC();  mma_p<2>(acc, af, bfr);
        __builtin_amdgcn_s_barrier();
        ld_ap<3>(C, af, C.fA0);
        PH_SYNC();  mma_p<3>(acc, af, bfr);
        vmwait<4>();
        __builtin_amdgcn_s_barrier();
        ld_bp(C, bfr, C.fB1);
        ld_ap<0>(C, af, C.fA1);
        stage4p(C.sA + kk + 128, C.A0w);
        PH_SYNC();  mma_p<0>(acc, af, bfr);
        __builtin_amdgcn_s_barrier();
        ld_ap<1>(C, af, C.fA1);
        stage01p(C.sB + kk + 192, C.B1w);
        PH_SYNC();  mma_p<1>(acc, af, bfr);
        __builtin_amdgcn_s_barrier();
        ld_ap<2>(C, af, C.fA1);
        stage23p(C.sB + kk + 192, C.B1w);
        PH_SYNC();  mma_p<2>(acc, af, bfr);
        __builtin_amdgcn_s_barrier();
        ld_ap<3>(C, af, C.fA1);
        PH_SYNC();  mma_p<3>(acc, af, bfr);
        vmwait<4>();
        __builtin_amdgcn_s_barrier();
    }
    {
        const int kk = (NIT - 1) * 128;
        ld_bp(C, bfr, C.fB0);
        ld_ap<0>(C, af, C.fA0);
        stage4p(C.sA + kk + 64, C.A1w);
        PH_SYNC();  mma_p<0>(acc, af, bfr);
        __builtin_amdgcn_s_barrier();
        ld_ap<1>(C, af, C.fA0); PH_SYNC(); mma_p<1>(acc, af, bfr); __builtin_amdgcn_s_barrier();
        ld_ap<2>(C, af, C.fA0); PH_SYNC(); mma_p<2>(acc, af, bfr); __builtin_amdgcn_s_barrier();
        ld_ap<3>(C, af, C.fA0); PH_SYNC(); mma_p<3>(acc, af, bfr);
        vmwait<0>();
        __builtin_amdgcn_s_barrier();
        ld_bp(C, bfr, C.fB1);
        ld_ap<0>(C, af, C.fA1); PH_SYNC(); mma_p<0>(acc, af, bfr); __builtin_amdgcn_s_barrier();
        ld_ap<1>(C, af, C.fA1); PH_SYNC(); mma_p<1>(acc, af, bfr); __builtin_amdgcn_s_barrier();
        ld_ap<2>(C, af, C.fA1); PH_SYNC(); mma_p<2>(acc, af, bfr); __builtin_amdgcn_s_barrier();
        ld_ap<3>(C, af, C.fA1); PH_SYNC(); mma_p<3>(acc, af, bfr);
    }
}

// ------ QKV GEMM on CoreP: M=4096 N=3072 K=1024, 128^2 tiles, 768 blocks ---
__global__ __launch_bounds__(256, 2) void gemm_qkv_k(
    const unsigned short* __restrict__ A, const unsigned short* __restrict__ Bt,
    const float* __restrict__ b0, const float* __restrict__ b1,
    const float* __restrict__ b2,
    unsigned short* __restrict__ oQ, unsigned short* __restrict__ oK,
    unsigned short* __restrict__ oV)
{
    extern __shared__ unsigned short LDS[];
    const int ob = blockIdx.x;                 // 768 blocks, %8==0 -> bijective
    const int wg = (ob & 7) * 96 + (ob >> 3);  // XCD-contiguous chunks of 96
    const int by = wg / 24, bx = wg - by*24;   // 32 x 24 tile grid
    const int bm = by * 128, bn = bx * 128;

    CoreP C;
    corep_setup(C, LDS, A, Bt, bm, bn, 0);

    f32x4 acc[4][4];
    #pragma unroll
    for (int i = 0; i < 4; ++i)
        #pragma unroll
        for (int j = 0; j < 4; ++j) acc[i][j] = (f32x4){0.f,0.f,0.f,0.f};

    corep_kloop<8>(C, acc);

    const int tid = threadIdx.x;
    const int w = tid >> 6, lane = tid & 63;
    const int quad = lane >> 4, l16 = lane & 15;
    const int wm = w >> 1, wn = w & 1;
    const int seg = bn >> 10;                  // uniform: 128 | 1024
    const int cb  = bn & 1023;
    if (seg < 2) {
        unsigned short* O = (seg == 0) ? oQ : oK;
        const float sc = (seg == 0) ? QSCALE : 1.0f;
        const float* bias = (seg == 0) ? b0 : b1;
        #pragma unroll
        for (int n = 0; n < 4; ++n) {
            const int col = cb + wn*64 + n*16 + l16;
            const float bs = bias[col];
            #pragma unroll
            for (int m = 0; m < 4; ++m)
                #pragma unroll
                for (int r = 0; r < 4; ++r) {
                    const int grow = bm + wm*64 + m*16 + quad*4 + r;
                    O[(size_t)grow*1024 + col] = f2bf((acc[m][n][r] + bs) * sc);
                }
        }
    } else {
        #pragma unroll
        for (int n = 0; n < 4; ++n) {
            const int ch = cb + wn*64 + n*16 + l16;
            const float bs = b2[ch];
            #pragma unroll
            for (int m = 0; m < 4; ++m) {
                const int grow0 = bm + wm*64 + m*16 + quad*4;
                us4 o;
                #pragma unroll
                for (int r = 0; r < 4; ++r) o[r] = f2bf(acc[m][n][r] + bs);
                *(us4*)&oV[(size_t)ch*MROW + grow0] = o;
            }
        }
    }
}

// ------ proj GEMM: CoreP 128x128, split-K=2 -> 512 blocks (round-4 best) ---
__global__ __launch_bounds__(256, 2) void gemm_proj_k(
    const unsigned short* __restrict__ A, const unsigned short* __restrict__ Bt,
    unsigned short* __restrict__ P)   // [2][MROW][1024]
{
    extern __shared__ unsigned short LDS[];
    const int ob = blockIdx.x;                // 256 blocks, %8==0 -> bijective
    const int wg = (ob & 7) * 32 + (ob >> 3);
    const int by = wg >> 3, bx = wg & 7;
    const int kz = blockIdx.y;
    const int bm = by * 128, bn = bx * 128;

    CoreP C;
    corep_setup(C, LDS, A, Bt, bm, bn, kz * 512);

    f32x4 acc[4][4];
    #pragma unroll
    for (int i = 0; i < 4; ++i)
        #pragma unroll
        for (int j = 0; j < 4; ++j) acc[i][j] = (f32x4){0.f,0.f,0.f,0.f};

    corep_kloop<4>(C, acc);

    const int tid = threadIdx.x;
    const int w = tid >> 6, lane = tid & 63;
    const int quad = lane >> 4, l16 = lane & 15;
    const int wm = w >> 1, wn = w & 1;
    unsigned short* O = P + (size_t)kz*MROW*1024;
    #pragma unroll
    for (int n = 0; n < 4; ++n) {
        const int col = bn + wn*64 + n*16 + l16;
        #pragma unroll
        for (int m = 0; m < 4; ++m)
            #pragma unroll
            for (int r = 0; r < 4; ++r) {
                const int grow = bm + wm*64 + m*16 + quad*4 + r;
                O[(size_t)grow*1024 + col] = f2bf(acc[m][n][r]);
            }
    }
}

// ---------------- flash attention v6 (measured-best: 43.1 us) --------------
__global__ __launch_bounds__(256, 4) void attn_k(
    const unsigned short* __restrict__ Qg,
    const unsigned short* __restrict__ Kg,
    const unsigned short* __restrict__ Vtg,
    unsigned short* __restrict__ CTX)
{
    extern __shared__ __align__(16) char lds_raw[];
    unsigned short* Ks = (unsigned short*)lds_raw;            // [64][64] swz
    unsigned short* Vs = (unsigned short*)(lds_raw + 8192);   // [64 d][64 kv] swz
    unsigned short* Qs = (unsigned short*)lds_raw;            // [64][72] transient
    float* Od = (float*)lds_raw;                              // [2][32][68] transient
    float* Ld = (float*)(lds_raw + 17408);                    // [64]

    const int tid  = threadIdx.x;
    const int wv   = tid >> 6;
    const int lane = tid & 63;
    const int quad = lane >> 4;
    const int l16  = lane & 15;
    const int wq   = wv & 1;
    const int wk   = wv >> 1;

    const int n    = blockIdx.x;
    const int slot = n >> 3;
    const int grp  = (n & 7) + 8 * (slot >> 5);
    const int qx   = slot & 31;
    const int h    = grp >> 1;
    const int b    = grp & 1;
    const int qb   = qx * 64;

    {   // Q: 64 rows x 64 cols -> Qs[64][72]
        const int r  = tid >> 2;
        const int cb = (tid & 3) * 16;
        const unsigned short* Qrow = Qg + ((size_t)(b*TSEQ + qb + r))*DMOD + h*HDIM + cb;
        *(us8*)&Qs[r*72 + cb]     = *(const us8*)&Qrow[0];
        *(us8*)&Qs[r*72 + cb + 8] = *(const us8*)&Qrow[8];
    }
    __syncthreads();
    bf16x8 qf[2][2];
    #pragma unroll
    for (int nt = 0; nt < 2; ++nt)
        #pragma unroll
        for (int kh = 0; kh < 2; ++kh)
            qf[nt][kh] = *(const bf16x8*)&Qs[(wq*32 + nt*16 + l16)*72 + kh*32 + quad*8];
    __syncthreads();   // Qs region free for K/V staging

    const int sr = lane >> 3;
    const int sc = lane & 7;
    const bool isK = (wv < 2);
    const int part = wv & 1;
    const unsigned short* gbase;
    unsigned int goff[4];
    unsigned short* ldst;
    if (isK) {
        gbase = Kg + ((size_t)(b*TSEQ))*DMOD + h*HDIM;
        #pragma unroll
        for (int s = 0; s < 4; ++s) {
            const int R = part*32 + s*8 + sr;
            const int gc = sc ^ ((R ^ (R >> 2)) & 7);
            goff[s] = (unsigned)(R*DMOD + gc*8);
        }
        ldst = Ks + part*2048;
    } else {
        gbase = Vtg + ((size_t)(h*HDIM))*MROW + b*TSEQ;
        #pragma unroll
        for (int s = 0; s < 4; ++s) {
            const int D = part*32 + s*8 + sr;
            const int gc = sc ^ (D & 7);
            goff[s] = (unsigned)(D*MROW + gc*8);
        }
        ldst = Vs + part*2048;
    }
    const size_t gstep = isK ? (size_t)64*DMOD : (size_t)64;

    const int rowA_l = (l16 >> 2)*8 + (l16 & 3);
    const int rA = wk*32 + rowA_l;
    const int rB = rA + 4;
    const int swA = ((rA ^ (rA >> 2)) & 7);
    const int swB = ((rB ^ (rB >> 2)) & 7);
    const unsigned short* kA0 = &Ks[rA*64 + ( quad      ^ swA)*8];
    const unsigned short* kA1 = &Ks[rA*64 + ((4 + quad) ^ swA)*8];
    const unsigned short* kB0 = &Ks[rB*64 + ( quad      ^ swB)*8];
    const unsigned short* kB1 = &Ks[rB*64 + ((4 + quad) ^ swB)*8];
    const unsigned short* vp[4];
    #pragma unroll
    for (int dt = 0; dt < 4; ++dt)
        vp[dt] = &Vs[(dt*16 + l16)*64 + ((wk*4 + quad) ^ (l16 & 7))*8];

    bf16x8 onef;
    { union { unsigned short u[8]; bf16x8 v; } o1;
      #pragma unroll
      for (int i = 0; i < 8; ++i) o1.u[i] = 0x3F80;
      onef = o1.v; }

    f32x4 oacc[4][2];
    f32x4 lacc[2];
    #pragma unroll
    for (int dt = 0; dt < 4; ++dt)
        #pragma unroll
        for (int nt = 0; nt < 2; ++nt) oacc[dt][nt] = (f32x4){0.f,0.f,0.f,0.f};
    lacc[0] = (f32x4){0.f,0.f,0.f,0.f};
    lacc[1] = (f32x4){0.f,0.f,0.f,0.f};

    #pragma unroll 1
    for (int it = 0; it < 32; ++it) {
        __syncthreads();
        #pragma unroll
        for (int s = 0; s < 4; ++s)
            gld_lds16(gbase + (size_t)it*gstep + goff[s], ldst + s*512);
        __syncthreads();

        bf16x8 ka0 = *(const bf16x8*)kA0;
        bf16x8 ka1 = *(const bf16x8*)kA1;
        bf16x8 kb0 = *(const bf16x8*)kB0;
        bf16x8 kb1 = *(const bf16x8*)kB1;
        bf16x8 vf[4];
        #pragma unroll
        for (int dt = 0; dt < 4; ++dt) vf[dt] = *(const bf16x8*)vp[dt];

        bf16x8 pf[2];
        #pragma unroll
        for (int nt = 0; nt < 2; ++nt) {
            f32x4 z = (f32x4){0.f,0.f,0.f,0.f};
            z = __builtin_amdgcn_mfma_f32_16x16x32_bf16(ka0, qf[nt][0], z, 0, 0, 0);
            f32x4 sA = __builtin_amdgcn_mfma_f32_16x16x32_bf16(ka1, qf[nt][1], z, 0, 0, 0);
            f32x4 z2 = (f32x4){0.f,0.f,0.f,0.f};
            z2 = __builtin_amdgcn_mfma_f32_16x16x32_bf16(kb0, qf[nt][0], z2, 0, 0, 0);
            f32x4 sB = __builtin_amdgcn_mfma_f32_16x16x32_bf16(kb1, qf[nt][1], z2, 0, 0, 0);
            float eA[4], eB[4];
            #pragma unroll
            for (int r = 0; r < 4; ++r) { eA[r] = fexp2(sA[r]); eB[r] = fexp2(sB[r]); }
            union { unsigned d[4]; bf16x8 v; } up;
            up.d[0] = __builtin_amdgcn_perm(__float_as_uint(eA[1]), __float_as_uint(eA[0]), 0x07060302);
            up.d[1] = __builtin_amdgcn_perm(__float_as_uint(eA[3]), __float_as_uint(eA[2]), 0x07060302);
            up.d[2] = __builtin_amdgcn_perm(__float_as_uint(eB[1]), __float_as_uint(eB[0]), 0x07060302);
            up.d[3] = __builtin_amdgcn_perm(__float_as_uint(eB[3]), __float_as_uint(eB[2]), 0x07060302);
            pf[nt] = up.v;
        }
        __builtin_amdgcn_s_setprio(1);
        #pragma unroll
        for (int nt = 0; nt < 2; ++nt) {
            lacc[nt] = __builtin_amdgcn_mfma_f32_16x16x32_bf16(onef, pf[nt], lacc[nt], 0, 0, 0);
            #pragma unroll
            for (int dt = 0; dt < 4; ++dt)
                oacc[dt][nt] = __builtin_amdgcn_mfma_f32_16x16x32_bf16(vf[dt], pf[nt], oacc[dt][nt], 0, 0, 0);
        }
        __builtin_amdgcn_s_setprio(0);
    }

    __syncthreads();   // all K/V reads done; Od/Ld overlay now safe
    if (wk == 0) {
        float* od = Od + wq*32*68;
        #pragma unroll
        for (int nt = 0; nt < 2; ++nt) {
            #pragma unroll
            for (int dt = 0; dt < 4; ++dt)
                *(f32x4*)&od[(nt*16 + l16)*68 + dt*16 + quad*4] = oacc[dt][nt];
            if (quad == 0) Ld[wq*32 + nt*16 + l16] = lacc[nt][0];
        }
    }
    __syncthreads();
    if (wk == 1) {
        const float* od = Od + wq*32*68;
        #pragma unroll
        for (int nt = 0; nt < 2; ++nt) {
            const float l = Ld[wq*32 + nt*16 + l16] + lacc[nt][0];
            const float inv = 1.f / l;
            const int q = qb + wq*32 + nt*16 + l16;
            unsigned short* crow = CTX + ((size_t)(b*TSEQ + q))*DMOD + h*HDIM;
            #pragma unroll
            for (int dt = 0; dt < 4; ++dt) {
                f32x4 p = *(const f32x4*)&od[(nt*16 + l16)*68 + dt*16 + quad*4];
                us4 o;
                #pragma unroll
                for (int r = 0; r < 4; ++r) o[r] = f2bf((p[r] + oacc[dt][nt][r]) * inv);
                *(us4*)&crow[dt*16 + quad*4] = o;
            }
        }
    }
}

// ---------- split-K reduce + bias + residual + LayerNorm -------------------
__global__ __launch_bounds__(256) void red_ln_k(
    const float* __restrict__ x, const unsigned short* __restrict__ P,
    const float* __restrict__ bo,
    const float* __restrict__ gamma, const float* __restrict__ beta,
    float* __restrict__ out)
{
    __shared__ float rs[4], rss[4];
    const int row = blockIdx.x;
    const int tid = threadIdx.x;
    const int c = tid * 4;
    const float4 xv = *(const float4*)&x[(size_t)row*DMOD + c];
    const us4 p0 = *(const us4*)&P[(size_t)row*DMOD + c];
    const us4 p1 = *(const us4*)&P[(size_t)(MROW + row)*DMOD + c];
    const float4 bv4 = *(const float4*)&bo[c];
    const float v0 = xv.x + bf2f(p0[0]) + bf2f(p1[0]) + bv4.x;
    const float v1 = xv.y + bf2f(p0[1]) + bf2f(p1[1]) + bv4.y;
    const float v2 = xv.z + bf2f(p0[2]) + bf2f(p1[2]) + bv4.z;
    const float v3 = xv.w + bf2f(p0[3]) + bf2f(p1[3]) + bv4.w;
    float s  = v0 + v1 + v2 + v3;
    float ss = v0*v0 + v1*v1 + v2*v2 + v3*v3;
    #pragma unroll
    for (int o = 32; o > 0; o >>= 1) {
        s  += __shfl_down(s,  o, 64);
        ss += __shfl_down(ss, o, 64);
    }
    if ((tid & 63) == 0) { rs[tid >> 6] = s; rss[tid >> 6] = ss; }
    __syncthreads();
    s  = rs[0] + rs[1] + rs[2] + rs[3];
    ss = rss[0] + rss[1] + rss[2] + rss[3];
    const float mean = s * (1.f/DMOD);
    const float var  = ss * (1.f/DMOD) - mean*mean;
    const float rstd = rsqrtf(var + LNEPS);
    const float4 gv = *(const float4*)&gamma[c];
    const float4 bv = *(const float4*)&beta[c];
    float4 o;
    o.x = (v0 - mean)*rstd*gv.x + bv.x;
    o.y = (v1 - mean)*rstd*gv.y + bv.y;
    o.z = (v2 - mean)*rstd*gv.z + bv.z;
    o.w = (v3 - mean)*rstd*gv.w + bv.w;
    *(float4*)&out[(size_t)row*DMOD + c] = o;
}

extern "C" void kernel_launch(void* const* d_in, const int* in_sizes, int n_in,
                              void* d_out, int out_size, void* d_ws, size_t ws_size,
                              hipStream_t stream) {
    const float* x     = (const float*)d_in[0];
    const float* wq    = (const float*)d_in[1];
    const float* bq    = (const float*)d_in[2];
    const float* wk    = (const float*)d_in[3];
    const float* bk    = (const float*)d_in[4];
    const float* wvp   = (const float*)d_in[5];
    const float* bvp   = (const float*)d_in[6];
    const float* wo    = (const float*)d_in[7];
    const float* bo    = (const float*)d_in[8];
    const float* gamma = (const float*)d_in[9];
    const float* beta  = (const float*)d_in[10];
    float* out = (float*)d_out;

    // ws layout (bf16 elems)
    unsigned short* Xb    = (unsigned short*)d_ws;          // [4096][1024]
    unsigned short* WqkvT = Xb    + (size_t)MROW*DMOD;      // [3072][1024]
    unsigned short* WoT   = WqkvT + (size_t)3072*1024;      // [1024][1024]
    unsigned short* Qb    = WoT   + (size_t)1024*1024;      // [4096][1024]
    unsigned short* Kb    = Qb    + (size_t)MROW*DMOD;      // [4096][1024]
    unsigned short* VtG   = Kb    + (size_t)MROW*DMOD;      // [1024][4096]
    unsigned short* CTXb  = VtG   + (size_t)DMOD*MROW;      // [4096][1024]
    unsigned short* Pp    = CTXb  + (size_t)MROW*DMOD;      // [2][4096][1024]

    prep_k<<<3072, 256, 0, stream>>>(x, wq, wk, wvp, wo, Xb, WqkvT, WoT);

    gemm_qkv_k<<<dim3(768), 256, 65536, stream>>>(
        Xb, WqkvT, bq, bk, bvp, Qb, Kb, VtG);

    attn_k<<<dim3(1024), 256, 17664, stream>>>(Qb, Kb, VtG, CTXb);

    gemm_proj_k<<<dim3(256, 2), 256, 65536, stream>>>(CTXb, WoT, Pp);

    red_ln_k<<<MROW, 256, 0, stream>>>(x, Pp, bo, gamma, beta, out);
}